// Round 1
// baseline (402.847 us; speedup 1.0000x reference)
//
#include <hip/hip_runtime.h>
#include <hip/hip_bf16.h>

typedef __bf16 bf16;
typedef __bf16 bf16x8 __attribute__((ext_vector_type(8)));
typedef __bf16 bf16x4 __attribute__((ext_vector_type(4)));
typedef float f32x4 __attribute__((ext_vector_type(4)));

#define MFMA16(a, b, c) __builtin_amdgcn_mfma_f32_16x16x32_bf16((a), (b), (c), 0, 0, 0)

constexpr int S = 4096;
constexpr int E = 1024;
constexpr int H = 16;
constexpr int HD = 64;
constexpr float NEG = -1e30f;

__device__ inline bf16x8 load_f32x8_as_bf16(const float* __restrict__ p) {
  float4 u0 = *reinterpret_cast<const float4*>(p);
  float4 u1 = *reinterpret_cast<const float4*>(p + 4);
  bf16x8 r;
  r[0] = (bf16)u0.x; r[1] = (bf16)u0.y; r[2] = (bf16)u0.z; r[3] = (bf16)u0.w;
  r[4] = (bf16)u1.x; r[5] = (bf16)u1.y; r[6] = (bf16)u1.z; r[7] = (bf16)u1.w;
  return r;
}

// ---------------- wo -> bf16 ----------------
__global__ __launch_bounds__(256) void cvt_wo_kernel(const float* __restrict__ wo,
                                                     bf16* __restrict__ wob) {
  int i = (blockIdx.x * 256 + threadIdx.x) * 4;
  float4 f = *reinterpret_cast<const float4*>(wo + i);
  bf16x4 b;
  b[0] = (bf16)f.x; b[1] = (bf16)f.y; b[2] = (bf16)f.z; b[3] = (bf16)f.w;
  *reinterpret_cast<bf16x4*>(wob + i) = b;
}

// ---------------- QKV projection ----------------
// Q[h][s][o] = sum_d x[s][h*64+d] * wq[h][o][d]   (Q pre-scaled by 0.125)
__global__ __launch_bounds__(256) void qkv_kernel(
    const float* __restrict__ x, const float* __restrict__ wq,
    const float* __restrict__ wk, const float* __restrict__ wv,
    bf16* __restrict__ qb, bf16* __restrict__ kb, bf16* __restrict__ vb) {
  const int h = blockIdx.y;
  const int s0 = blockIdx.x * 64;
  const int w = threadIdx.x >> 6;
  const int l = threadIdx.x & 63;
  const int lg = l >> 4, lr = l & 15;

  // A fragment: rows = x rows (s), k = d
  bf16x8 af[2];
  {
    const float* xp = x + (size_t)(s0 + w * 16 + lr) * E + h * HD;
    af[0] = load_f32x8_as_bf16(xp + lg * 8);
    af[1] = load_f32x8_as_bf16(xp + 32 + lg * 8);
  }
  const float* Wsrc[3] = {wq + (size_t)h * HD * HD, wk + (size_t)h * HD * HD,
                          wv + (size_t)h * HD * HD};
  bf16* Odst[3] = {qb, kb, vb};
#pragma unroll
  for (int pj = 0; pj < 3; ++pj) {
    f32x4 acc[4];
#pragma unroll
    for (int ot = 0; ot < 4; ++ot) acc[ot] = f32x4{0.f, 0.f, 0.f, 0.f};
#pragma unroll
    for (int ks = 0; ks < 2; ++ks) {
#pragma unroll
      for (int ot = 0; ot < 4; ++ot) {
        // B[k=d][n=o] = W[o][d]: lane holds col o=lr, k = 8*lg + i
        bf16x8 bfr = load_f32x8_as_bf16(Wsrc[pj] + (size_t)(ot * 16 + lr) * HD + ks * 32 + lg * 8);
        acc[ot] = MFMA16(af[ks], bfr, acc[ot]);
      }
    }
    const float scale = (pj == 0) ? 0.125f : 1.0f;
    bf16* op = Odst[pj] + (size_t)h * S * HD;
#pragma unroll
    for (int ot = 0; ot < 4; ++ot)
#pragma unroll
      for (int r = 0; r < 4; ++r)
        op[(size_t)(s0 + w * 16 + lg * 4 + r) * HD + ot * 16 + lr] =
            (bf16)(acc[ot][r] * scale);
  }
}

// ---------------- causal flash attention ----------------
__global__ __launch_bounds__(256) void attn_kernel(
    const bf16* __restrict__ qb, const bf16* __restrict__ kb,
    const bf16* __restrict__ vb, bf16* __restrict__ ob) {
  __shared__ __align__(16) bf16 Vt[64][72];      // [d][kv], padded rows (144 B)
  __shared__ __align__(16) bf16 Pl[4][16][72];   // per-wave [q][kv]
  const int h = blockIdx.y;
  const int q0 = (gridDim.x - 1 - blockIdx.x) * 64;  // heavy blocks first
  const int tid = threadIdx.x;
  const int w = tid >> 6, l = tid & 63, lg = l >> 4, lr = l & 15;

  // Q fragments (B operand of S^T mfma): lane owns q-col = lr
  bf16x8 qf[2];
  {
    const bf16* qp = qb + ((size_t)h * S + q0 + w * 16 + lr) * HD;
    qf[0] = *reinterpret_cast<const bf16x8*>(qp + lg * 8);
    qf[1] = *reinterpret_cast<const bf16x8*>(qp + 32 + lg * 8);
  }
  f32x4 Ot[4];  // O^T accumulator: row d = dt*16 + lg*4 + r, col q = lr
#pragma unroll
  for (int i = 0; i < 4; ++i) Ot[i] = f32x4{0.f, 0.f, 0.f, 0.f};
  float mrun = NEG, lsum = 0.f;

  const int nkv = q0 / 64 + 1;
  for (int kvb = 0; kvb < nkv; ++kvb) {
    const int kv0 = kvb * 64;
    __syncthreads();  // previous iteration's Vt fully consumed
    // stage V transposed: Vt[d][kv]
    {
      const int kv = tid & 63, dg = (tid >> 6) * 16;
      const bf16* vp = vb + ((size_t)h * S + kv0 + kv) * HD + dg;
      bf16x8 v0 = *reinterpret_cast<const bf16x8*>(vp);
      bf16x8 v1 = *reinterpret_cast<const bf16x8*>(vp + 8);
#pragma unroll
      for (int i = 0; i < 8; ++i) Vt[dg + i][kv] = v0[i];
#pragma unroll
      for (int i = 0; i < 8; ++i) Vt[dg + 8 + i][kv] = v1[i];
    }
    // S^T tiles: mfma(A=K rows, B=Q cols) -> D[kv][q]
    float st[4][4];
#pragma unroll
    for (int sub = 0; sub < 4; ++sub) {
      const bf16* kp = kb + ((size_t)h * S + kv0 + sub * 16 + lr) * HD;
      f32x4 acc = f32x4{0.f, 0.f, 0.f, 0.f};
      acc = MFMA16(*reinterpret_cast<const bf16x8*>(kp + lg * 8), qf[0], acc);
      acc = MFMA16(*reinterpret_cast<const bf16x8*>(kp + 32 + lg * 8), qf[1], acc);
#pragma unroll
      for (int r = 0; r < 4; ++r) st[sub][r] = acc[r];
    }
    // causal mask: only the diagonal kv-block needs it
    if (kv0 == q0) {
      const int q = q0 + w * 16 + lr;
#pragma unroll
      for (int sub = 0; sub < 4; ++sub)
#pragma unroll
        for (int r = 0; r < 4; ++r)
          if (kv0 + sub * 16 + lg * 4 + r > q) st[sub][r] = NEG;
    }
    // online softmax over kv (per q = lr; kv spread over 4 lane-groups x 16 regs)
    float tmax = NEG;
#pragma unroll
    for (int sub = 0; sub < 4; ++sub)
#pragma unroll
      for (int r = 0; r < 4; ++r) tmax = fmaxf(tmax, st[sub][r]);
    tmax = fmaxf(tmax, __shfl_xor(tmax, 16));
    tmax = fmaxf(tmax, __shfl_xor(tmax, 32));
    const float mnew = fmaxf(mrun, tmax);
    const float alpha = __expf(mrun - mnew);
    float psum = 0.f;
#pragma unroll
    for (int sub = 0; sub < 4; ++sub)
#pragma unroll
      for (int r = 0; r < 4; ++r) {
        float p = __expf(st[sub][r] - mnew);
        bf16 pb = (bf16)p;
        Pl[w][lr][sub * 16 + lg * 4 + r] = pb;
        psum += (float)pb;
      }
    psum += __shfl_xor(psum, 16);
    psum += __shfl_xor(psum, 32);
    lsum = lsum * alpha + psum;
    mrun = mnew;
#pragma unroll
    for (int dt = 0; dt < 4; ++dt) Ot[dt] *= alpha;
    __syncthreads();  // Vt staged + Pl visible (Pl is per-wave; barrier also orders it)
    // PV: O^T[d][q] += V^T[d][kv] @ P[kv][q]
#pragma unroll
    for (int ks = 0; ks < 2; ++ks) {
      bf16x8 pf = *reinterpret_cast<const bf16x8*>(&Pl[w][lr][ks * 32 + lg * 8]);
#pragma unroll
      for (int dt = 0; dt < 4; ++dt) {
        bf16x8 vf = *reinterpret_cast<const bf16x8*>(&Vt[dt * 16 + lr][ks * 32 + lg * 8]);
        Ot[dt] = MFMA16(vf, pf, Ot[dt]);
      }
    }
  }
  const float inv = 1.0f / lsum;
#pragma unroll
  for (int dt = 0; dt < 4; ++dt)
#pragma unroll
    for (int r = 0; r < 4; ++r)
      ob[(size_t)(q0 + w * 16 + lr) * E + h * HD + dt * 16 + lg * 4 + r] =
          (bf16)(Ot[dt][r] * inv);
}

// ---------------- output projection: out = attn @ wo^T ----------------
__global__ __launch_bounds__(256) void out_gemm_kernel(
    const bf16* __restrict__ ob, const bf16* __restrict__ wob,
    float* __restrict__ out) {
  const int w = threadIdx.x >> 6, l = threadIdx.x & 63, lg = l >> 4, lr = l & 15;
  const int s0 = blockIdx.x * 64, e0 = blockIdx.y * 64;
  f32x4 acc[4];
#pragma unroll
  for (int i = 0; i < 4; ++i) acc[i] = f32x4{0.f, 0.f, 0.f, 0.f};
  const bf16* ap = ob + (size_t)(s0 + w * 16 + lr) * E;
  for (int k = 0; k < E; k += 32) {
    bf16x8 af = *reinterpret_cast<const bf16x8*>(ap + k + lg * 8);
#pragma unroll
    for (int ct = 0; ct < 4; ++ct) {
      bf16x8 bfr = *reinterpret_cast<const bf16x8*>(
          wob + (size_t)(e0 + ct * 16 + lr) * E + k + lg * 8);
      acc[ct] = MFMA16(af, bfr, acc[ct]);
    }
  }
#pragma unroll
  for (int ct = 0; ct < 4; ++ct)
#pragma unroll
    for (int r = 0; r < 4; ++r)
      out[(size_t)(s0 + w * 16 + lg * 4 + r) * E + e0 + ct * 16 + lr] = acc[ct][r];
}

extern "C" void kernel_launch(void* const* d_in, const int* in_sizes, int n_in,
                              void* d_out, int out_size, void* d_ws, size_t ws_size,
                              hipStream_t stream) {
  const float* x  = (const float*)d_in[0];
  const float* wq = (const float*)d_in[1];
  const float* wk = (const float*)d_in[2];
  const float* wv = (const float*)d_in[3];
  const float* wo = (const float*)d_in[4];
  float* out = (float*)d_out;

  bf16* qb  = (bf16*)d_ws;                 // [H][S][HD]
  bf16* kb  = qb + (size_t)H * S * HD;     // [H][S][HD]
  bf16* vb  = kb + (size_t)H * S * HD;     // [H][S][HD]
  bf16* ob  = vb + (size_t)H * S * HD;     // [S][E]
  bf16* wob = ob + (size_t)S * E;          // [E][E]

  cvt_wo_kernel<<<dim3(E * E / 1024), 256, 0, stream>>>(wo, wob);
  qkv_kernel<<<dim3(S / 64, H), 256, 0, stream>>>(x, wq, wk, wv, qb, kb, vb);
  attn_kernel<<<dim3(S / 64, H), 256, 0, stream>>>(qb, kb, vb, ob);
  out_gemm_kernel<<<dim3(S / 64, E / 64), 256, 0, stream>>>(ob, wob, out);
}

// Round 2
// 251.150 us; speedup vs baseline: 1.6040x; 1.6040x over previous
//
#include <hip/hip_runtime.h>
#include <hip/hip_bf16.h>

typedef __bf16 bf16;
typedef __bf16 bf16x8 __attribute__((ext_vector_type(8)));
typedef __bf16 bf16x4 __attribute__((ext_vector_type(4)));
typedef float f32x4 __attribute__((ext_vector_type(4)));
typedef float f32x16 __attribute__((ext_vector_type(16)));

#define MFMA16(a, b, c) __builtin_amdgcn_mfma_f32_16x16x32_bf16((a), (b), (c), 0, 0, 0)
#define MFMA32(a, b, c) __builtin_amdgcn_mfma_f32_32x32x16_bf16((a), (b), (c), 0, 0, 0)

constexpr int S = 4096;
constexpr int E = 1024;
constexpr int H = 16;
constexpr int HD = 64;
constexpr float NEG = -1e30f;

__device__ inline f32x16 fzero16() {
  f32x16 z;
#pragma unroll
  for (int i = 0; i < 16; ++i) z[i] = 0.f;
  return z;
}

__device__ inline bf16x8 load_f32x8_as_bf16(const float* __restrict__ p) {
  float4 u0 = *reinterpret_cast<const float4*>(p);
  float4 u1 = *reinterpret_cast<const float4*>(p + 4);
  bf16x8 r;
  r[0] = (bf16)u0.x; r[1] = (bf16)u0.y; r[2] = (bf16)u0.z; r[3] = (bf16)u0.w;
  r[4] = (bf16)u1.x; r[5] = (bf16)u1.y; r[6] = (bf16)u1.z; r[7] = (bf16)u1.w;
  return r;
}

// ---------------- wo -> bf16 ----------------
__global__ __launch_bounds__(256) void cvt_wo_kernel(const float* __restrict__ wo,
                                                     bf16* __restrict__ wob) {
  int i = (blockIdx.x * 256 + threadIdx.x) * 4;
  float4 f = *reinterpret_cast<const float4*>(wo + i);
  bf16x4 b;
  b[0] = (bf16)f.x; b[1] = (bf16)f.y; b[2] = (bf16)f.z; b[3] = (bf16)f.w;
  *reinterpret_cast<bf16x4*>(wob + i) = b;
}

// ---------------- QKV projection ----------------
__global__ __launch_bounds__(256) void qkv_kernel(
    const float* __restrict__ x, const float* __restrict__ wq,
    const float* __restrict__ wk, const float* __restrict__ wv,
    bf16* __restrict__ qb, bf16* __restrict__ kb, bf16* __restrict__ vb) {
  const int h = blockIdx.y;
  const int s0 = blockIdx.x * 64;
  const int w = threadIdx.x >> 6;
  const int l = threadIdx.x & 63;
  const int lg = l >> 4, lr = l & 15;

  bf16x8 af[2];
  {
    const float* xp = x + (size_t)(s0 + w * 16 + lr) * E + h * HD;
    af[0] = load_f32x8_as_bf16(xp + lg * 8);
    af[1] = load_f32x8_as_bf16(xp + 32 + lg * 8);
  }
  const float* Wsrc[3] = {wq + (size_t)h * HD * HD, wk + (size_t)h * HD * HD,
                          wv + (size_t)h * HD * HD};
  bf16* Odst[3] = {qb, kb, vb};
#pragma unroll
  for (int pj = 0; pj < 3; ++pj) {
    f32x4 acc[4];
#pragma unroll
    for (int ot = 0; ot < 4; ++ot) acc[ot] = f32x4{0.f, 0.f, 0.f, 0.f};
#pragma unroll
    for (int ks = 0; ks < 2; ++ks) {
#pragma unroll
      for (int ot = 0; ot < 4; ++ot) {
        bf16x8 bfr = load_f32x8_as_bf16(Wsrc[pj] + (size_t)(ot * 16 + lr) * HD + ks * 32 + lg * 8);
        acc[ot] = MFMA16(af[ks], bfr, acc[ot]);
      }
    }
    const float scale = (pj == 0) ? 0.125f : 1.0f;
    bf16* op = Odst[pj] + (size_t)h * S * HD;
#pragma unroll
    for (int ot = 0; ot < 4; ++ot)
#pragma unroll
      for (int r = 0; r < 4; ++r)
        op[(size_t)(s0 + w * 16 + lg * 4 + r) * HD + ot * 16 + lr] =
            (bf16)(acc[ot][r] * scale);
  }
}

// ---------------- causal flash attention, 32x32 MFMA, in-register P ----------------
// 4 waves/block, each wave owns 32 q-cols (QBLK=128). KV staged 64 at a time,
// V transposed in LDS (double-buffered, 1 barrier/stage). Swapped QK^T:
// S^T[kv][q] = mfma32(A=K, B=Q); P stays in registers, redistributed across
// half-waves with 4 shfl_xor(32) per 32-kv tile to form PV B-fragments.
__global__ __launch_bounds__(256) void attn_kernel(
    const bf16* __restrict__ qb, const bf16* __restrict__ kb,
    const bf16* __restrict__ vb, bf16* __restrict__ ob) {
  __shared__ __align__(16) bf16 Vt[2][64][72];  // [buf][d][kv] padded
  const int s = blockIdx.x;
  const int head = (s & 255) >> 4;
  const int j = s & 15;
  const int qt = (s < 256) ? (31 - j) : j;  // heavy tiles dispatched first; (b, b+256) = same head, work sums to 66
  const int tid = threadIdx.x;
  const int w = tid >> 6, l = tid & 63;
  const int lo = l & 31, hi = l >> 5;
  const int q0w = qt * 128 + w * 32;
  const int nst = 2 * qt + 2;

  // Q fragments (B operand): col q = q0w+lo, k = dt*16 + hi*8 + jj
  bf16x8 qf[4];
  {
    const bf16* qp = qb + ((size_t)head * S + q0w + lo) * HD + hi * 8;
#pragma unroll
    for (int dt = 0; dt < 4; ++dt) qf[dt] = *reinterpret_cast<const bf16x8*>(qp + dt * 16);
  }
  f32x16 acc0 = fzero16(), acc1 = fzero16();  // O^T d-halves; row d = dh*32+(r&3)+8*(r>>2)+4*hi, col q = lo
  float mrun = NEG, lsum = 0.f;

  // stage V^T[d][kv] for a 64-kv block
  auto stage = [&](int buf, int st) {
    const int kv = tid & 63, dg = (tid >> 6) * 16;
    const bf16* vp = vb + ((size_t)head * S + st * 64 + kv) * HD + dg;
    bf16x8 v0 = *reinterpret_cast<const bf16x8*>(vp);
    bf16x8 v1 = *reinterpret_cast<const bf16x8*>(vp + 8);
#pragma unroll
    for (int i = 0; i < 8; ++i) Vt[buf][dg + i][kv] = v0[i];
#pragma unroll
    for (int i = 0; i < 8; ++i) Vt[buf][dg + 8 + i][kv] = v1[i];
  };

  stage(0, 0);
  __syncthreads();

  for (int st = 0; st < nst; ++st) {
    const int kv0 = st * 64;
    const int buf = st & 1;
    if (st + 1 < nst) stage(buf ^ 1, st + 1);  // overlaps compute (other buffer)

    // S^T[kv][q]: two 32-kv tiles, K loaded direct from global (L1/L2-resident)
    f32x16 sv[2];
#pragma unroll
    for (int t = 0; t < 2; ++t) {
      f32x16 a = fzero16();
      const bf16* kp = kb + ((size_t)head * S + kv0 + t * 32 + lo) * HD + hi * 8;
#pragma unroll
      for (int dt = 0; dt < 4; ++dt)
        a = MFMA32(*reinterpret_cast<const bf16x8*>(kp + dt * 16), qf[dt], a);
      sv[t] = a;
    }
    // causal mask (only near-diagonal stages enter)
    if (kv0 + 63 > q0w) {
      const int q = q0w + lo;
#pragma unroll
      for (int t = 0; t < 2; ++t)
#pragma unroll
        for (int r = 0; r < 16; ++r) {
          int kv = kv0 + t * 32 + (r & 3) + 8 * (r >> 2) + 4 * hi;
          if (kv > q) sv[t][r] = NEG;
        }
    }
    // online softmax (per q = lo; kv split across hi halves)
    float tmax = NEG;
#pragma unroll
    for (int t = 0; t < 2; ++t)
#pragma unroll
      for (int r = 0; r < 16; ++r) tmax = fmaxf(tmax, sv[t][r]);
    tmax = fmaxf(tmax, __shfl_xor(tmax, 32));
    const float mnew = fmaxf(mrun, tmax);
    const float alpha = __expf(mrun - mnew);
    float psum = 0.f;
#pragma unroll
    for (int t = 0; t < 2; ++t)
#pragma unroll
      for (int r = 0; r < 16; ++r) {
        sv[t][r] = __expf(sv[t][r] - mnew);
        psum += sv[t][r];
      }
    psum += __shfl_xor(psum, 32);
    lsum = lsum * alpha + psum;
    mrun = mnew;
#pragma unroll
    for (int i = 0; i < 16; ++i) { acc0[i] *= alpha; acc1[i] *= alpha; }

    // P -> bf16 in-register; half-wave exchange; PV
#pragma unroll
    for (int t = 0; t < 2; ++t) {
      unsigned wv[8];
#pragma unroll
      for (int i = 0; i < 8; ++i) {
        union { unsigned u; bf16 h[2]; } pu;
        pu.h[0] = (bf16)sv[t][2 * i];
        pu.h[1] = (bf16)sv[t][2 * i + 1];
        wv[i] = pu.u;
      }
      // lane hi=0 holds kv {4t'..}, needs partner's; see layout derivation
      unsigned e0 = (unsigned)__shfl_xor((int)(hi ? wv[0] : wv[2]), 32);
      unsigned e1 = (unsigned)__shfl_xor((int)(hi ? wv[1] : wv[3]), 32);
      unsigned e2 = (unsigned)__shfl_xor((int)(hi ? wv[4] : wv[6]), 32);
      unsigned e3 = (unsigned)__shfl_xor((int)(hi ? wv[5] : wv[7]), 32);
      union { bf16x8 v; unsigned u[4]; } B0, B1;
      B0.u[0] = hi ? e0 : wv[0]; B0.u[1] = hi ? e1 : wv[1];
      B0.u[2] = hi ? wv[2] : e0; B0.u[3] = hi ? wv[3] : e1;
      B1.u[0] = hi ? e2 : wv[4]; B1.u[1] = hi ? e3 : wv[5];
      B1.u[2] = hi ? wv[6] : e2; B1.u[3] = hi ? wv[7] : e3;
#pragma unroll
      for (int dh = 0; dh < 2; ++dh) {
        bf16x8 a0 = *reinterpret_cast<const bf16x8*>(&Vt[buf][dh * 32 + lo][t * 32 + hi * 8]);
        bf16x8 a1 = *reinterpret_cast<const bf16x8*>(&Vt[buf][dh * 32 + lo][t * 32 + 16 + hi * 8]);
        if (dh == 0) { acc0 = MFMA32(a0, B0.v, acc0); acc0 = MFMA32(a1, B1.v, acc0); }
        else         { acc1 = MFMA32(a0, B0.v, acc1); acc1 = MFMA32(a1, B1.v, acc1); }
      }
    }
    __syncthreads();
  }

  const float inv = 1.0f / lsum;
#pragma unroll
  for (int dh = 0; dh < 2; ++dh) {
#pragma unroll
    for (int r = 0; r < 16; ++r) {
      int d = dh * 32 + (r & 3) + 8 * (r >> 2) + 4 * hi;
      float v = (dh == 0) ? acc0[r] : acc1[r];
      ob[(size_t)(q0w + lo) * E + head * HD + d] = (bf16)(v * inv);
    }
  }
}

// ---------------- output projection: out = attn @ wo^T (128x64 tiles) ----------------
__global__ __launch_bounds__(256) void out_gemm_kernel(
    const bf16* __restrict__ ob, const bf16* __restrict__ wob,
    float* __restrict__ out) {
  const int w = threadIdx.x >> 6, l = threadIdx.x & 63, lg = l >> 4, lr = l & 15;
  const int s0 = blockIdx.x * 128, e0 = blockIdx.y * 64;
  f32x4 acc[2][4];
#pragma unroll
  for (int i = 0; i < 2; ++i)
#pragma unroll
    for (int jj = 0; jj < 4; ++jj) acc[i][jj] = f32x4{0.f, 0.f, 0.f, 0.f};
  const bf16* ap0 = ob + (size_t)(s0 + w * 16 + lr) * E;
  const bf16* ap1 = ap0 + (size_t)64 * E;
  for (int k = 0; k < E; k += 32) {
    bf16x8 a0 = *reinterpret_cast<const bf16x8*>(ap0 + k + lg * 8);
    bf16x8 a1 = *reinterpret_cast<const bf16x8*>(ap1 + k + lg * 8);
#pragma unroll
    for (int ct = 0; ct < 4; ++ct) {
      bf16x8 bfr = *reinterpret_cast<const bf16x8*>(
          wob + (size_t)(e0 + ct * 16 + lr) * E + k + lg * 8);
      acc[0][ct] = MFMA16(a0, bfr, acc[0][ct]);
      acc[1][ct] = MFMA16(a1, bfr, acc[1][ct]);
    }
  }
#pragma unroll
  for (int half = 0; half < 2; ++half)
#pragma unroll
    for (int ct = 0; ct < 4; ++ct)
#pragma unroll
      for (int r = 0; r < 4; ++r)
        out[(size_t)(s0 + half * 64 + w * 16 + lg * 4 + r) * E + e0 + ct * 16 + lr] =
            acc[half][ct][r];
}

extern "C" void kernel_launch(void* const* d_in, const int* in_sizes, int n_in,
                              void* d_out, int out_size, void* d_ws, size_t ws_size,
                              hipStream_t stream) {
  const float* x  = (const float*)d_in[0];
  const float* wq = (const float*)d_in[1];
  const float* wk = (const float*)d_in[2];
  const float* wv = (const float*)d_in[3];
  const float* wo = (const float*)d_in[4];
  float* out = (float*)d_out;

  bf16* qb  = (bf16*)d_ws;                 // [H][S][HD]
  bf16* kb  = qb + (size_t)H * S * HD;     // [H][S][HD]
  bf16* vb  = kb + (size_t)H * S * HD;     // [H][S][HD]
  bf16* ob  = vb + (size_t)H * S * HD;     // [S][E]
  bf16* wob = ob + (size_t)S * E;          // [E][E]

  cvt_wo_kernel<<<dim3(E * E / 1024), 256, 0, stream>>>(wo, wob);
  qkv_kernel<<<dim3(S / 64, H), 256, 0, stream>>>(x, wq, wk, wv, qb, kb, vb);
  attn_kernel<<<dim3(512), 256, 0, stream>>>(qb, kb, vb, ob);
  out_gemm_kernel<<<dim3(S / 128, E / 64), 256, 0, stream>>>(ob, wob, out);
}

// Round 3
// 223.626 us; speedup vs baseline: 1.8014x; 1.1231x over previous
//
#include <hip/hip_runtime.h>
#include <hip/hip_bf16.h>

typedef __bf16 bf16;
typedef __bf16 bf16x8 __attribute__((ext_vector_type(8)));
typedef __bf16 bf16x4 __attribute__((ext_vector_type(4)));
typedef float f32x4 __attribute__((ext_vector_type(4)));
typedef float f32x16 __attribute__((ext_vector_type(16)));

#define MFMA16(a, b, c) __builtin_amdgcn_mfma_f32_16x16x32_bf16((a), (b), (c), 0, 0, 0)
#define MFMA32(a, b, c) __builtin_amdgcn_mfma_f32_32x32x16_bf16((a), (b), (c), 0, 0, 0)

constexpr int S = 4096;
constexpr int E = 1024;
constexpr int H = 16;
constexpr int HD = 64;
constexpr float NEG = -1e30f;
// scores in log2 domain: fold 1/sqrt(64) * log2(e) into Q
constexpr float QSCALE = 0.125f * 1.44269504088896f;

__device__ inline f32x16 fzero16() {
  f32x16 z;
#pragma unroll
  for (int i = 0; i < 16; ++i) z[i] = 0.f;
  return z;
}

__device__ inline bf16x8 load_f32x8_as_bf16(const float* __restrict__ p) {
  float4 u0 = *reinterpret_cast<const float4*>(p);
  float4 u1 = *reinterpret_cast<const float4*>(p + 4);
  bf16x8 r;
  r[0] = (bf16)u0.x; r[1] = (bf16)u0.y; r[2] = (bf16)u0.z; r[3] = (bf16)u0.w;
  r[4] = (bf16)u1.x; r[5] = (bf16)u1.y; r[6] = (bf16)u1.z; r[7] = (bf16)u1.w;
  return r;
}

// ---------------- wo -> bf16 ----------------
__global__ __launch_bounds__(256) void cvt_wo_kernel(const float* __restrict__ wo,
                                                     bf16* __restrict__ wob) {
  int i = (blockIdx.x * 256 + threadIdx.x) * 4;
  float4 f = *reinterpret_cast<const float4*>(wo + i);
  bf16x4 b;
  b[0] = (bf16)f.x; b[1] = (bf16)f.y; b[2] = (bf16)f.z; b[3] = (bf16)f.w;
  *reinterpret_cast<bf16x4*>(wob + i) = b;
}

// ---------------- QKV projection ----------------
// Q pre-scaled by QSCALE; V written TRANSPOSED: vt[h][d][s]
__global__ __launch_bounds__(256) void qkv_kernel(
    const float* __restrict__ x, const float* __restrict__ wq,
    const float* __restrict__ wk, const float* __restrict__ wv,
    bf16* __restrict__ qb, bf16* __restrict__ kb, bf16* __restrict__ vt) {
  const int h = blockIdx.y;
  const int s0 = blockIdx.x * 64;
  const int w = threadIdx.x >> 6;
  const int l = threadIdx.x & 63;
  const int lg = l >> 4, lr = l & 15;

  bf16x8 af[2];
  {
    const float* xp = x + (size_t)(s0 + w * 16 + lr) * E + h * HD;
    af[0] = load_f32x8_as_bf16(xp + lg * 8);
    af[1] = load_f32x8_as_bf16(xp + 32 + lg * 8);
  }
  const float* Wsrc[3] = {wq + (size_t)h * HD * HD, wk + (size_t)h * HD * HD,
                          wv + (size_t)h * HD * HD};
#pragma unroll
  for (int pj = 0; pj < 3; ++pj) {
    f32x4 acc[4];
#pragma unroll
    for (int ot = 0; ot < 4; ++ot) acc[ot] = f32x4{0.f, 0.f, 0.f, 0.f};
#pragma unroll
    for (int ks = 0; ks < 2; ++ks) {
#pragma unroll
      for (int ot = 0; ot < 4; ++ot) {
        bf16x8 bfr = load_f32x8_as_bf16(Wsrc[pj] + (size_t)(ot * 16 + lr) * HD + ks * 32 + lg * 8);
        acc[ot] = MFMA16(af[ks], bfr, acc[ot]);
      }
    }
    if (pj == 2) {
      // V^T store: vt[(h*HD + o)][s], 4 consecutive s per lane-group
#pragma unroll
      for (int ot = 0; ot < 4; ++ot) {
        bf16x4 b;
#pragma unroll
        for (int r = 0; r < 4; ++r) b[r] = (bf16)acc[ot][r];
        *reinterpret_cast<bf16x4*>(vt + (size_t)(h * HD + ot * 16 + lr) * S +
                                   s0 + w * 16 + lg * 4) = b;
      }
    } else {
      const float scale = (pj == 0) ? QSCALE : 1.0f;
      bf16* op = ((pj == 0) ? qb : kb) + (size_t)h * S * HD;
#pragma unroll
      for (int ot = 0; ot < 4; ++ot)
#pragma unroll
        for (int r = 0; r < 4; ++r)
          op[(size_t)(s0 + w * 16 + lg * 4 + r) * HD + ot * 16 + lr] =
              (bf16)(acc[ot][r] * scale);
    }
  }
}

// ---------------- causal flash attention: LDS-free, barrier-free ----------------
// 4 waves/block, wave owns 32 q-cols. K from kb[h][s][d] (A rows), V from
// vt[h][d][s] (A rows of V^T) — both contiguous bf16x8 global loads, L1/L2-hot.
// Swapped QK^T (S^T = mfma32(K, Q)); P in-register, half-wave shfl exchange.
__global__ __launch_bounds__(256) void attn_kernel(
    const bf16* __restrict__ qb, const bf16* __restrict__ kb,
    const bf16* __restrict__ vt, bf16* __restrict__ ob) {
  const int s = blockIdx.x;
  const int head = (s & 255) >> 4;
  const int j = s & 15;
  const int qt = (s < 256) ? (31 - j) : j;  // heavy first; (b, b+256) pair sums to 66 stages
  const int tid = threadIdx.x;
  const int w = tid >> 6, l = tid & 63;
  const int lo = l & 31, hi = l >> 5;
  const int q0w = qt * 128 + w * 32;
  const int nst = 2 * qt + 2;

  bf16x8 qf[4];
  {
    const bf16* qp = qb + ((size_t)head * S + q0w + lo) * HD + hi * 8;
#pragma unroll
    for (int dt = 0; dt < 4; ++dt) qf[dt] = *reinterpret_cast<const bf16x8*>(qp + dt * 16);
  }
  const bf16* kbase = kb + (size_t)head * S * HD;
  const bf16* vbase = vt + (size_t)head * HD * S;

  f32x16 acc0 = fzero16(), acc1 = fzero16();
  float mrun = NEG, lsum = 0.f;

  for (int st = 0; st < nst; ++st) {
    const int kv0 = st * 64;
    // --- S^T[kv][q] = K @ Q ---
    f32x16 sv[2];
#pragma unroll
    for (int t = 0; t < 2; ++t) {
      f32x16 a = fzero16();
      const bf16* kp = kbase + (size_t)(kv0 + t * 32 + lo) * HD + hi * 8;
#pragma unroll
      for (int dt = 0; dt < 4; ++dt)
        a = MFMA32(*reinterpret_cast<const bf16x8*>(kp + dt * 16), qf[dt], a);
      sv[t] = a;
    }
    // --- issue V^T loads early (hide L2 latency under softmax VALU) ---
    bf16x8 vf[2][2][2];  // [t][dh][half-of-16k]
#pragma unroll
    for (int t = 0; t < 2; ++t)
#pragma unroll
      for (int dh = 0; dh < 2; ++dh) {
        const bf16* vp = vbase + (size_t)(dh * 32 + lo) * S + kv0 + t * 32 + hi * 8;
        vf[t][dh][0] = *reinterpret_cast<const bf16x8*>(vp);
        vf[t][dh][1] = *reinterpret_cast<const bf16x8*>(vp + 16);
      }
    // --- causal mask (near-diagonal stages only) ---
    if (kv0 + 63 > q0w) {
      const int q = q0w + lo;
#pragma unroll
      for (int t = 0; t < 2; ++t)
#pragma unroll
        for (int r = 0; r < 16; ++r) {
          int kv = kv0 + t * 32 + (r & 3) + 8 * (r >> 2) + 4 * hi;
          if (kv > q) sv[t][r] = NEG;
        }
    }
    // --- online softmax, log2 domain, defer-max ---
    float tmax = NEG;
#pragma unroll
    for (int t = 0; t < 2; ++t)
#pragma unroll
      for (int r = 0; r < 16; ++r) tmax = fmaxf(tmax, sv[t][r]);
    if (!__all(tmax <= mrun + 8.f)) {
      float tm = fmaxf(tmax, __shfl_xor(tmax, 32));
      float mnew = fmaxf(mrun, tm);
      float alpha = exp2f(mrun - mnew);
      lsum *= alpha;
#pragma unroll
      for (int i = 0; i < 16; ++i) { acc0[i] *= alpha; acc1[i] *= alpha; }
      mrun = mnew;
    }
    float psum = 0.f;
#pragma unroll
    for (int t = 0; t < 2; ++t)
#pragma unroll
      for (int r = 0; r < 16; ++r) {
        sv[t][r] = exp2f(sv[t][r] - mrun);
        psum += sv[t][r];
      }
    lsum += psum;
    // --- P -> bf16, half-wave exchange, PV ---
#pragma unroll
    for (int t = 0; t < 2; ++t) {
      unsigned wv[8];
#pragma unroll
      for (int i = 0; i < 8; ++i) {
        union { unsigned u; bf16 h2[2]; } pu;
        pu.h2[0] = (bf16)sv[t][2 * i];
        pu.h2[1] = (bf16)sv[t][2 * i + 1];
        wv[i] = pu.u;
      }
      unsigned e0 = (unsigned)__shfl_xor((int)(hi ? wv[0] : wv[2]), 32);
      unsigned e1 = (unsigned)__shfl_xor((int)(hi ? wv[1] : wv[3]), 32);
      unsigned e2 = (unsigned)__shfl_xor((int)(hi ? wv[4] : wv[6]), 32);
      unsigned e3 = (unsigned)__shfl_xor((int)(hi ? wv[5] : wv[7]), 32);
      union { bf16x8 v; unsigned u[4]; } B0, B1;
      B0.u[0] = hi ? e0 : wv[0]; B0.u[1] = hi ? e1 : wv[1];
      B0.u[2] = hi ? wv[2] : e0; B0.u[3] = hi ? wv[3] : e1;
      B1.u[0] = hi ? e2 : wv[4]; B1.u[1] = hi ? e3 : wv[5];
      B1.u[2] = hi ? wv[6] : e2; B1.u[3] = hi ? wv[7] : e3;
      acc0 = MFMA32(vf[t][0][0], B0.v, acc0);
      acc0 = MFMA32(vf[t][0][1], B1.v, acc0);
      acc1 = MFMA32(vf[t][1][0], B0.v, acc1);
      acc1 = MFMA32(vf[t][1][1], B1.v, acc1);
    }
  }

  const float inv = 1.0f / (lsum + __shfl_xor(lsum, 32));
  bf16* obp = ob + (size_t)(q0w + lo) * E + head * HD;
#pragma unroll
  for (int dh = 0; dh < 2; ++dh)
#pragma unroll
    for (int g = 0; g < 4; ++g) {
      bf16x4 b;
#pragma unroll
      for (int r = 0; r < 4; ++r)
        b[r] = (bf16)(((dh == 0) ? acc0[g * 4 + r] : acc1[g * 4 + r]) * inv);
      *reinterpret_cast<bf16x4*>(obp + dh * 32 + 8 * g + 4 * hi) = b;
    }
}

// ---------------- output projection: out = attn @ wo^T (128x64 tiles) ----------------
__global__ __launch_bounds__(256) void out_gemm_kernel(
    const bf16* __restrict__ ob, const bf16* __restrict__ wob,
    float* __restrict__ out) {
  const int w = threadIdx.x >> 6, l = threadIdx.x & 63, lg = l >> 4, lr = l & 15;
  const int s0 = blockIdx.x * 128, e0 = blockIdx.y * 64;
  f32x4 acc[2][4];
#pragma unroll
  for (int i = 0; i < 2; ++i)
#pragma unroll
    for (int jj = 0; jj < 4; ++jj) acc[i][jj] = f32x4{0.f, 0.f, 0.f, 0.f};
  const bf16* ap0 = ob + (size_t)(s0 + w * 16 + lr) * E;
  const bf16* ap1 = ap0 + (size_t)64 * E;
  for (int k = 0; k < E; k += 32) {
    bf16x8 a0 = *reinterpret_cast<const bf16x8*>(ap0 + k + lg * 8);
    bf16x8 a1 = *reinterpret_cast<const bf16x8*>(ap1 + k + lg * 8);
#pragma unroll
    for (int ct = 0; ct < 4; ++ct) {
      bf16x8 bfr = *reinterpret_cast<const bf16x8*>(
          wob + (size_t)(e0 + ct * 16 + lr) * E + k + lg * 8);
      acc[0][ct] = MFMA16(a0, bfr, acc[0][ct]);
      acc[1][ct] = MFMA16(a1, bfr, acc[1][ct]);
    }
  }
#pragma unroll
  for (int half = 0; half < 2; ++half)
#pragma unroll
    for (int ct = 0; ct < 4; ++ct)
#pragma unroll
      for (int r = 0; r < 4; ++r)
        out[(size_t)(s0 + half * 64 + w * 16 + lg * 4 + r) * E + e0 + ct * 16 + lr] =
            acc[half][ct][r];
}

extern "C" void kernel_launch(void* const* d_in, const int* in_sizes, int n_in,
                              void* d_out, int out_size, void* d_ws, size_t ws_size,
                              hipStream_t stream) {
  const float* x  = (const float*)d_in[0];
  const float* wq = (const float*)d_in[1];
  const float* wk = (const float*)d_in[2];
  const float* wv = (const float*)d_in[3];
  const float* wo = (const float*)d_in[4];
  float* out = (float*)d_out;

  bf16* qb  = (bf16*)d_ws;                 // [H][S][HD]
  bf16* kb  = qb + (size_t)H * S * HD;     // [H][S][HD]
  bf16* vt  = kb + (size_t)H * S * HD;     // [H][HD][S]  (V transposed)
  bf16* ob  = vt + (size_t)H * S * HD;     // [S][E]
  bf16* wob = ob + (size_t)S * E;          // [E][E]

  cvt_wo_kernel<<<dim3(E * E / 1024), 256, 0, stream>>>(wo, wob);
  qkv_kernel<<<dim3(S / 64, H), 256, 0, stream>>>(x, wq, wk, wv, qb, kb, vt);
  attn_kernel<<<dim3(512), 256, 0, stream>>>(qb, kb, vt, ob);
  out_gemm_kernel<<<dim3(S / 128, E / 64), 256, 0, stream>>>(ob, wob, out);
}